// Round 2
// baseline (321.862 us; speedup 1.0000x reference)
//
#include <hip/hip_runtime.h>
#include <math.h>

#define B_    16
#define C_    256
#define NPIX  4096      // H*W
#define K_    4
#define HID_  512
#define ITERS_ 3
#define NROWS (B_*NPIX) // 65536
#define EPS_  1e-8f

typedef __attribute__((ext_vector_type(8))) short bf16x8;
typedef __attribute__((ext_vector_type(4))) float f32x4;

__device__ __forceinline__ float gelu_f(float x) {
    return 0.5f * x * (1.0f + erff(x * 0.70710678118654752f));
}

__device__ __forceinline__ unsigned short f2bf(float x) {
    union { float f; unsigned u; } v; v.f = x;
    unsigned r = v.u + 0x7fffu + ((v.u >> 16) & 1u);   // round-nearest-even
    return (unsigned short)(r >> 16);
}
__device__ __forceinline__ float bflo(unsigned u) {
    union { unsigned u; float f; } v; v.u = u << 16; return v.f;
}
__device__ __forceinline__ float bfhi(unsigned u) {
    union { unsigned u; float f; } v; v.u = u & 0xffff0000u; return v.f;
}
__device__ __forceinline__ float4 shfl_xor4(float4 v, int m) {
    v.x = __shfl_xor(v.x, m); v.y = __shfl_xor(v.y, m);
    v.z = __shfl_xor(v.z, m); v.w = __shfl_xor(v.w, m);
    return v;
}
__device__ __forceinline__ void fma4(float4& a, const float4 w, const float4 s) {
    a.x = fmaf(w.x, s.x, a.x); a.y = fmaf(w.y, s.y, a.y);
    a.z = fmaf(w.z, s.z, a.z); a.w = fmaf(w.w, s.w, a.w);
}
__device__ __forceinline__ float hsum4(const float4 a) {
    return (a.x + a.y) + (a.z + a.w);
}

// 1024-thread block, reduce 256-entry red1/red2 arrays (writers stored before call)
__device__ __forceinline__ void reduce256_in1024(float* red1, float* red2, int tid,
                                                 float& o1, float& o2) {
    __syncthreads();
    for (int s = 128; s > 0; s >>= 1) {
        if (tid < s) { red1[tid] += red1[tid + s]; red2[tid] += red2[tid + s]; }
        __syncthreads();
    }
    o1 = red1[0]; o2 = red2[0];
    __syncthreads();
}

// ---------------- prep: float4-packed weights ----------------
// Wq4[c4][d]   = {Wq[d][4c4..]}      (16384)
// Wu4[c4][d]   = {Wu[d][4c4..]}      (32768)
// W14[c4][h]   = {W1[h][4c4..]}      (32768)
// W24[h4][d]   = {W2[d][4h4..]}      (32768)
// We14[c4][e]  = {We1[e][4c4..]}     (8192)
// Wkq4[d4][c]  = {Wk[4d4+j][c]}      (16384)  -- for qt = q . Wk
// Wv4[e4][d]   = {Wv[d][4e4..]}      (16384)  -- for updates = Wv . u'
__global__ void prep_kernel(const float* __restrict__ Wq, const float* __restrict__ Wu,
                            const float* __restrict__ W1, const float* __restrict__ W2,
                            const float* __restrict__ We1, const float* __restrict__ Wk,
                            const float* __restrict__ Wv,
                            float4* __restrict__ Wq4, float4* __restrict__ Wu4,
                            float4* __restrict__ W14, float4* __restrict__ W24,
                            float4* __restrict__ We14, float4* __restrict__ Wkq4,
                            float4* __restrict__ Wv4) {
    int i = blockIdx.x * 256 + threadIdx.x;        // float4 index, 0..155647
    if (i < 16384) {
        int c4 = i >> 8, d = i & 255;
        Wq4[i] = *(const float4*)&Wq[d * 256 + c4 * 4];
    } else if (i < 49152) {
        int j = i - 16384; int c4 = j >> 8, d = j & 255;
        Wu4[j] = *(const float4*)&Wu[d * 512 + c4 * 4];
    } else if (i < 81920) {
        int j = i - 49152; int c4 = j >> 9, h = j & 511;
        W14[j] = *(const float4*)&W1[h * 256 + c4 * 4];
    } else if (i < 114688) {
        int j = i - 81920; int h4 = j >> 8, d = j & 255;
        W24[j] = *(const float4*)&W2[d * 512 + h4 * 4];
    } else if (i < 122880) {
        int j = i - 114688; int c4 = j >> 7, e = j & 127;
        We14[j] = *(const float4*)&We1[e * 256 + c4 * 4];
    } else if (i < 139264) {
        int j = i - 122880; int d4 = j >> 8, c = j & 255;
        float4 o;
        o.x = Wk[(4 * d4 + 0) * 256 + c];
        o.y = Wk[(4 * d4 + 1) * 256 + c];
        o.z = Wk[(4 * d4 + 2) * 256 + c];
        o.w = Wk[(4 * d4 + 3) * 256 + c];
        Wkq4[j] = o;
    } else {
        int j = i - 139264; int e4 = j >> 8, d = j & 255;
        Wv4[j] = *(const float4*)&Wv[d * 256 + e4 * 4];
    }
}

// ---------------- fused LN(+stats) + transpose + bf16 convert, single x pass ----------------
__global__ __launch_bounds__(256) void xn_fused_kernel(
    const float* __restrict__ x, const float* __restrict__ g, const float* __restrict__ bta,
    unsigned short* __restrict__ xnb) {
    __shared__ float tile[256][65];
    __shared__ float sg[256], sb[256];
    __shared__ float red1[256], red2[256];
    __shared__ float smean[64], srstd[64];
    const int tid = threadIdx.x;
    const int nt = blockIdx.x << 6, b = blockIdx.y;

    sg[tid] = g[tid]; sb[tid] = bta[tid];
    #pragma unroll
    for (int r = 0; r < 64; ++r) {
        int idx = tid + (r << 8);
        int c_l = idx >> 6, n_l = idx & 63;
        tile[c_l][n_l] = x[(size_t)(b * C_ + c_l) * NPIX + nt + n_l];
    }
    __syncthreads();
    {
        int cq = tid >> 6, n_l = tid & 63;
        float s = 0.f, s2 = 0.f;
        #pragma unroll 8
        for (int c = cq * 64; c < cq * 64 + 64; ++c) {
            float v = tile[c][n_l];
            s += v; s2 += v * v;
        }
        red1[tid] = s; red2[tid] = s2;
    }
    __syncthreads();
    if (tid < 64) {
        float s  = red1[tid] + red1[tid + 64] + red1[tid + 128] + red1[tid + 192];
        float s2 = red2[tid] + red2[tid + 64] + red2[tid + 128] + red2[tid + 192];
        float m = s * (1.0f / C_);
        smean[tid] = m;
        srstd[tid] = rsqrtf(s2 * (1.0f / C_) - m * m + 1e-5f);
    }
    __syncthreads();
    #pragma unroll
    for (int r = 0; r < 32; ++r) {
        int idx = tid + (r << 8);
        int n_l = idx >> 7, cp = idx & 127;
        int c0 = cp << 1;
        float mn = smean[n_l], rs = srstd[n_l];
        float v0 = (tile[c0][n_l] - mn) * rs * sg[c0] + sb[c0];
        float v1 = (tile[c0 + 1][n_l] - mn) * rs * sg[c0 + 1] + sb[c0 + 1];
        ushort2 o; o.x = f2bf(v0); o.y = f2bf(v1);
        *reinterpret_cast<ushort2*>(&xnb[((size_t)(b * NPIX + nt + n_l)) * C_ + c0]) = o;
    }
}

// ---------------- slot kernels: 1024 threads, K split 4 ways (q = tid>>8) ----------------

// LN + q-projection + qt = q.Wk + qoff = q.bk
__device__ __forceinline__ void ln_q_qt_1024(
    float v, int tid, int d, int q, int r,
    const float* __restrict__ g_sl, const float* __restrict__ b_sl,
    const float4* __restrict__ Wq4, const float* __restrict__ bq,
    const float4* __restrict__ Wkq4, const float* __restrict__ bk,
    float* __restrict__ qtbuf, float* __restrict__ qoffbuf,
    float* snorm, float* qrow, float* pq, float* redA, float* redB) {
    if (q == 0) { redA[d] = v; redB[d] = v * v; }
    float sm, s2;
    reduce256_in1024(redA, redB, tid, sm, s2);
    if (q == 0) {
        float m = sm * (1.f / C_);
        float rs = rsqrtf(s2 * (1.f / C_) - m * m + 1e-5f);
        snorm[d] = (v - m) * rs * g_sl[d] + b_sl[d];
    }
    __syncthreads();
    // q projection (quarter over c)
    {
        const float4* sn4 = (const float4*)snorm;
        float4 a0 = {0,0,0,0}, a1 = {0,0,0,0};
        int c4b = q << 4;
        #pragma unroll
        for (int i = 0; i < 16; i += 2) {
            fma4(a0, Wq4[(c4b + i) * 256 + d], sn4[c4b + i]);
            fma4(a1, Wq4[(c4b + i + 1) * 256 + d], sn4[c4b + i + 1]);
        }
        pq[q * 256 + d] = hsum4(a0) + hsum4(a1);
    }
    __syncthreads();
    if (q == 0) {
        float qfull = pq[d] + pq[256 + d] + pq[512 + d] + pq[768 + d] + bq[d];
        qrow[d] = qfull;
        redA[d] = qfull * bk[d]; redB[d] = 0.f;
    }
    float qoffv, dummy;
    reduce256_in1024(redA, redB, tid, qoffv, dummy);
    if (tid == 0) qoffbuf[r] = qoffv;
    // qt = q . Wk (quarter over d-rows of Wk)
    {
        const float4* q4 = (const float4*)qrow;
        float4 a0 = {0,0,0,0}, a1 = {0,0,0,0};
        int d4b = q << 4;
        #pragma unroll
        for (int i = 0; i < 16; i += 2) {
            fma4(a0, Wkq4[(d4b + i) * 256 + d], q4[d4b + i]);
            fma4(a1, Wkq4[(d4b + i + 1) * 256 + d], q4[d4b + i + 1]);
        }
        pq[q * 256 + d] = hsum4(a0) + hsum4(a1);
    }
    __syncthreads();
    if (q == 0)
        qtbuf[r * C_ + d] = pq[d] + pq[256 + d] + pq[512 + d] + pq[768 + d];
}

__global__ __launch_bounds__(1024) void slot_init_q_kernel(
    const float* __restrict__ noise, const float* __restrict__ mu,
    const float* __restrict__ log_sigma,
    const float* __restrict__ g_sl, const float* __restrict__ b_sl,
    const float4* __restrict__ Wq4, const float* __restrict__ bq,
    const float4* __restrict__ Wkq4, const float* __restrict__ bk,
    float* __restrict__ slots, float* __restrict__ qtbuf, float* __restrict__ qoffbuf,
    float* __restrict__ usum, float* __restrict__ denom) {
    __shared__ __align__(16) float snorm[256];
    __shared__ __align__(16) float qrow[256];
    __shared__ float pq[1024];
    __shared__ float redA[256], redB[256];
    int tid = threadIdx.x;
    int d = tid & 255, q = tid >> 8;
    int r = blockIdx.x;
    float v = 0.f;
    if (q == 0) {
        v = mu[d] + expf(log_sigma[d]) * noise[r * C_ + d];
        slots[r * C_ + d] = v;
        usum[r * C_ + d] = 0.f;          // zero accumulators for first attn pass
    }
    if (tid == 0) denom[r] = 0.f;
    ln_q_qt_1024(v, tid, d, q, r, g_sl, b_sl, Wq4, bq, Wkq4, bk,
                 qtbuf, qoffbuf, snorm, qrow, pq, redA, redB);
}

// slot update core; returns ov (valid for q==0 threads)
__device__ __forceinline__ float slot_update_body(
    int tid, int d, int q, int r, const float* __restrict__ slots,
    float* __restrict__ usum, float* __restrict__ denom,
    const float4* __restrict__ Wv4, const float* __restrict__ bv,
    const float4* __restrict__ Wu4, const float* __restrict__ bu,
    const float* __restrict__ g_mlp, const float* __restrict__ b_mlp,
    const float4* __restrict__ W14, const float* __restrict__ b1,
    const float4* __restrict__ W24, const float* __restrict__ b2,
    float* comb, float* pq, float* mrow, float* hrow,
    float* redA, float* redB, float* s_denom, float* s_scale) {
    // phase 0: read accumulated u'' (atomically built by attn) + denom; re-zero for next iter
    float uv = 0.f;
    if (q == 0) {
        uv = usum[r * C_ + d];
        usum[r * C_ + d] = 0.f;
    }
    if (tid == 0) {
        float dv = denom[r];
        *s_denom = dv + EPS_;
        *s_scale = dv / (dv + EPS_);
        denom[r] = 0.f;
    }
    float prev = 0.f;
    if (q == 0) prev = slots[r * C_ + d];
    __syncthreads();
    if (q == 0) {
        comb[d] = prev;
        mrow[d] = uv / *s_denom;                 // u'
    }
    __syncthreads();
    // phase V: updates = Wv . u' + s*bv  (quarter over e)
    {
        const float4* u4 = (const float4*)mrow;
        float4 a0 = {0,0,0,0}, a1 = {0,0,0,0};
        int e4b = q << 4;
        #pragma unroll
        for (int i = 0; i < 16; i += 2) {
            fma4(a0, Wv4[(e4b + i) * 256 + d], u4[e4b + i]);
            fma4(a1, Wv4[(e4b + i + 1) * 256 + d], u4[e4b + i + 1]);
        }
        pq[q * 256 + d] = hsum4(a0) + hsum4(a1);
    }
    __syncthreads();
    if (q == 0)
        comb[256 + d] = pq[d] + pq[256 + d] + pq[512 + d] + pq[768 + d] + *s_scale * bv[d];
    __syncthreads();
    // phase 1: Wu (K=512), quarter = 32 c4
    const float4* cb4 = (const float4*)comb;
    {
        float4 a0 = {0,0,0,0}, a1 = {0,0,0,0}, a2 = {0,0,0,0}, a3 = {0,0,0,0};
        int c4b = q << 5;
        #pragma unroll
        for (int i = 0; i < 32; i += 4) {
            float4 w0 = Wu4[(c4b + i + 0) * 256 + d];
            float4 w1 = Wu4[(c4b + i + 1) * 256 + d];
            float4 w2 = Wu4[(c4b + i + 2) * 256 + d];
            float4 w3 = Wu4[(c4b + i + 3) * 256 + d];
            fma4(a0, w0, cb4[c4b + i + 0]); fma4(a1, w1, cb4[c4b + i + 1]);
            fma4(a2, w2, cb4[c4b + i + 2]); fma4(a3, w3, cb4[c4b + i + 3]);
        }
        pq[q * 256 + d] = (hsum4(a0) + hsum4(a1)) + (hsum4(a2) + hsum4(a3));
    }
    __syncthreads();
    float nv = 0.f;
    if (q == 0) {
        nv = pq[d] + pq[256 + d] + pq[512 + d] + pq[768 + d] + bu[d] + prev;
        redA[d] = nv; redB[d] = nv * nv;
    }
    float sm, s2;
    reduce256_in1024(redA, redB, tid, sm, s2);
    if (q == 0) {
        float m = sm * (1.f / C_);
        float rs = rsqrtf(s2 * (1.f / C_) - m * m + 1e-5f);
        mrow[d] = (nv - m) * rs * g_mlp[d] + b_mlp[d];
    }
    __syncthreads();
    // phase 2: W1 (K=256 -> 512 outputs), halves (h2 = tid>>9)
    const float4* m4 = (const float4*)mrow;
    {
        int j = tid & 511, h2 = tid >> 9;
        float4 a0 = {0,0,0,0}, a1 = {0,0,0,0};
        int c4b = h2 << 5;
        #pragma unroll
        for (int i = 0; i < 32; i += 2) {
            float4 w0 = W14[(c4b + i + 0) * 512 + j];
            float4 w1 = W14[(c4b + i + 1) * 512 + j];
            fma4(a0, w0, m4[c4b + i + 0]); fma4(a1, w1, m4[c4b + i + 1]);
        }
        pq[h2 * 512 + j] = hsum4(a0) + hsum4(a1);
    }
    __syncthreads();
    if (tid < 512) hrow[tid] = gelu_f(pq[tid] + pq[512 + tid] + b1[tid]);
    __syncthreads();
    // phase 3: W2 (K=512)
    const float4* h4 = (const float4*)hrow;
    {
        float4 a0 = {0,0,0,0}, a1 = {0,0,0,0}, a2 = {0,0,0,0}, a3 = {0,0,0,0};
        int h4b = q << 5;
        #pragma unroll
        for (int i = 0; i < 32; i += 4) {
            float4 w0 = W24[(h4b + i + 0) * 256 + d];
            float4 w1 = W24[(h4b + i + 1) * 256 + d];
            float4 w2 = W24[(h4b + i + 2) * 256 + d];
            float4 w3 = W24[(h4b + i + 3) * 256 + d];
            fma4(a0, w0, h4[h4b + i + 0]); fma4(a1, w1, h4[h4b + i + 1]);
            fma4(a2, w2, h4[h4b + i + 2]); fma4(a3, w3, h4[h4b + i + 3]);
        }
        pq[q * 256 + d] = (hsum4(a0) + hsum4(a1)) + (hsum4(a2) + hsum4(a3));
    }
    __syncthreads();
    float ov = 0.f;
    if (q == 0)
        ov = nv + pq[d] + pq[256 + d] + pq[512 + d] + pq[768 + d] + b2[d];
    return ov;
}

__global__ __launch_bounds__(1024) void slot_update_q_kernel(
    float* __restrict__ slots, float* __restrict__ usum, float* __restrict__ denom,
    const float4* __restrict__ Wv4, const float* __restrict__ bv,
    const float4* __restrict__ Wu4, const float* __restrict__ bu,
    const float* __restrict__ g_mlp, const float* __restrict__ b_mlp,
    const float4* __restrict__ W14, const float* __restrict__ b1,
    const float4* __restrict__ W24, const float* __restrict__ b2,
    const float* __restrict__ g_sl, const float* __restrict__ b_sl,
    const float4* __restrict__ Wq4, const float* __restrict__ bq,
    const float4* __restrict__ Wkq4, const float* __restrict__ bk,
    float* __restrict__ qtbuf, float* __restrict__ qoffbuf) {
    __shared__ __align__(16) float comb[512];
    __shared__ __align__(16) float mrow[256];
    __shared__ __align__(16) float hrow[512];
    __shared__ float pq[1024];
    __shared__ float redA[256], redB[256];
    __shared__ float s_denom, s_scale;
    int tid = threadIdx.x;
    int d = tid & 255, q = tid >> 8;
    int r = blockIdx.x;
    float ov = slot_update_body(tid, d, q, r, slots, usum, denom, Wv4, bv, Wu4, bu,
                                g_mlp, b_mlp, W14, b1, W24, b2,
                                comb, pq, mrow, hrow, redA, redB, &s_denom, &s_scale);
    if (q == 0) slots[r * C_ + d] = ov;
    __syncthreads();
    ln_q_qt_1024(ov, tid, d, q, r, g_sl, b_sl, Wq4, bq, Wkq4, bk,
                 qtbuf, qoffbuf, mrow, comb, pq, redA, redB);
}

__global__ __launch_bounds__(1024) void slot_update_final_kernel(
    float* __restrict__ slots, float* __restrict__ usum, float* __restrict__ denom,
    const float4* __restrict__ Wv4, const float* __restrict__ bv,
    const float4* __restrict__ Wu4, const float* __restrict__ bu,
    const float* __restrict__ g_mlp, const float* __restrict__ b_mlp,
    const float4* __restrict__ W14, const float* __restrict__ b1,
    const float4* __restrict__ W24, const float* __restrict__ b2,
    const float4* __restrict__ We14, const float* __restrict__ be1,
    const float* __restrict__ We2, const float* __restrict__ be2,
    float* __restrict__ out) {
    __shared__ __align__(16) float comb[512];
    __shared__ __align__(16) float mrow[256];
    __shared__ __align__(16) float hrow[512];
    __shared__ float pq[1024];
    __shared__ float redA[256], redB[256];
    __shared__ float s_denom, s_scale;
    __shared__ float erow[128];
    int tid = threadIdx.x;
    int d = tid & 255, q = tid >> 8;
    int r = blockIdx.x;
    float ov = slot_update_body(tid, d, q, r, slots, usum, denom, Wv4, bv, Wu4, bu,
                                g_mlp, b_mlp, W14, b1, W24, b2,
                                comb, pq, mrow, hrow, redA, redB, &s_denom, &s_scale);
    if (q == 0) {
        out[r * C_ + d] = ov;
        mrow[d] = ov;
    }
    __syncthreads();
    // We1: 128 outputs, 8-way K split (o8 = tid>>7, 8 c4 each)
    const float4* m4 = (const float4*)mrow;
    {
        int e = tid & 127, o8 = tid >> 7;
        float4 a0 = {0,0,0,0}, a1 = {0,0,0,0};
        int c4b = o8 << 3;
        #pragma unroll
        for (int i = 0; i < 8; i += 2) {
            fma4(a0, We14[(c4b + i) * 128 + e], m4[c4b + i]);
            fma4(a1, We14[(c4b + i + 1) * 128 + e], m4[c4b + i + 1]);
        }
        pq[o8 * 128 + e] = hsum4(a0) + hsum4(a1);
    }
    __syncthreads();
    if (tid < 128) {
        float s = 0.f;
        #pragma unroll
        for (int o = 0; o < 8; ++o) s += pq[o * 128 + tid];
        erow[tid] = gelu_f(s + be1[tid]);
    }
    __syncthreads();
    if (tid < 64) {
        float p = We2[tid] * erow[tid] + We2[tid + 64] * erow[tid + 64];
        #pragma unroll
        for (int m = 1; m <= 32; m <<= 1) p += __shfl_xor(p, m);
        if (tid == 0) out[B_ * K_ * C_ + r] = 1.0f / (1.0f + expf(-(p + be2[0])));
    }
}

// ---------------- fused attention: reads xnb directly (no k/v materialized) ----------------
// logits = qt.xn + qoff; u'' accumulated directly into usum via device-scope atomics
__global__ __launch_bounds__(256) void attn_fused_kernel(
    const float* __restrict__ qtbuf, const float* __restrict__ qoffbuf,
    const unsigned short* __restrict__ xnb,
    float* __restrict__ usum, float* __restrict__ denom) {
    __shared__ float4 qT[264];
    __shared__ float attns[K_][64];
    __shared__ float upd_s[K_][256];
    __shared__ float asw[4][4];
    __shared__ float4 qo_s;

    const int tid = threadIdx.x;
    const int b = blockIdx.y;
    const int chunk = blockIdx.x;
    const int n0 = chunk << 6;
    const int wave = tid >> 6, lane = tid & 63;

    {
        int c = tid;
        float4 qv;
        qv.x = qtbuf[b * 1024 + c];
        qv.y = qtbuf[b * 1024 + 256 + c];
        qv.z = qtbuf[b * 1024 + 512 + c];
        qv.w = qtbuf[b * 1024 + 768 + c];
        qT[c + (c >> 5)] = qv;
        if (tid == 0) qo_s = *(const float4*)&qoffbuf[b * 4];
    }
    __syncthreads();

    const int cpart = tid & 7;
    const int npair = tid >> 3;
    const int c0 = cpart << 5;
    float4 acc0 = {0.f, 0.f, 0.f, 0.f}, acc1 = {0.f, 0.f, 0.f, 0.f};
    const unsigned short* kbase = xnb + ((size_t)b * NPIX + n0 + npair * 2) * C_ + c0;
    #pragma unroll
    for (int j = 0; j < 4; ++j) {
        uint4 k0 = *reinterpret_cast<const uint4*>(kbase + j * 8);
        uint4 k1 = *reinterpret_cast<const uint4*>(kbase + C_ + j * 8);
        const unsigned kw0[4] = {k0.x, k0.y, k0.z, k0.w};
        const unsigned kw1[4] = {k1.x, k1.y, k1.z, k1.w};
        #pragma unroll
        for (int jj = 0; jj < 4; ++jj) {
            int cidx = c0 + j * 8 + jj * 2 + cpart;
            float4 qa = qT[cidx];
            float4 qb = qT[cidx + 1];
            float f00 = bflo(kw0[jj]), f01 = bfhi(kw0[jj]);
            float f10 = bflo(kw1[jj]), f11 = bfhi(kw1[jj]);
            acc0.x += f00 * qa.x + f01 * qb.x;  acc0.y += f00 * qa.y + f01 * qb.y;
            acc0.z += f00 * qa.z + f01 * qb.z;  acc0.w += f00 * qa.w + f01 * qb.w;
            acc1.x += f10 * qa.x + f11 * qb.x;  acc1.y += f10 * qa.y + f11 * qb.y;
            acc1.z += f10 * qa.z + f11 * qb.z;  acc1.w += f10 * qa.w + f11 * qb.w;
        }
    }
    #pragma unroll
    for (int m = 1; m <= 4; m <<= 1) {
        acc0 = acc0 + shfl_xor4(acc0, m);
        acc1 = acc1 + shfl_xor4(acc1, m);
    }
    float4 w0, w1;
    {
        float4 l = (acc0 + qo_s) * 0.0625f;
        float mx = fmaxf(fmaxf(l.x, l.y), fmaxf(l.z, l.w));
        w0.x = expf(l.x - mx); w0.y = expf(l.y - mx);
        w0.z = expf(l.z - mx); w0.w = expf(l.w - mx);
        float inv = 1.0f / (w0.x + w0.y + w0.z + w0.w);
        w0 = w0 * inv;
        l = (acc1 + qo_s) * 0.0625f;
        mx = fmaxf(fmaxf(l.x, l.y), fmaxf(l.z, l.w));
        w1.x = expf(l.x - mx); w1.y = expf(l.y - mx);
        w1.z = expf(l.z - mx); w1.w = expf(l.w - mx);
        inv = 1.0f / (w1.x + w1.y + w1.z + w1.w);
        w1 = w1 * inv;
    }
    if (cpart == 0) {
        int n_l = npair * 2;
        attns[0][n_l] = w0.x; attns[1][n_l] = w0.y; attns[2][n_l] = w0.z; attns[3][n_l] = w0.w;
        attns[0][n_l + 1] = w1.x; attns[1][n_l + 1] = w1.y;
        attns[2][n_l + 1] = w1.z; attns[3][n_l + 1] = w1.w;
    }
    float4 ws = w0 + w1;
    #pragma unroll
    for (int m = 8; m <= 32; m <<= 1) ws = ws + shfl_xor4(ws, m);
    if (lane == 0) {
        asw[wave][0] = ws.x; asw[wave][1] = ws.y; asw[wave][2] = ws.z; asw[wave][3] = ws.w;
    }
    __syncthreads();
    if (tid < 4)
        atomicAdd(&denom[b * 4 + tid],
                  asw[0][tid] + asw[1][tid] + asw[2][tid] + asw[3][tid]);

    const int h = wave >> 1;
    const int chalf = (wave & 1) << 7;
    const int c = chalf + lane * 2;
    float a0[K_] = {0.f, 0.f, 0.f, 0.f};
    float a1[K_] = {0.f, 0.f, 0.f, 0.f};
    const unsigned short* vbase = xnb + ((size_t)b * NPIX + n0 + h * 32) * C_ + c;
    #pragma unroll 4
    for (int nn = 0; nn < 32; ++nn) {
        unsigned vv = *reinterpret_cast<const unsigned*>(vbase + (size_t)nn * C_);
        float v0 = bflo(vv), v1 = bfhi(vv);
        int n_l = h * 32 + nn;
        float q0 = attns[0][n_l], q1 = attns[1][n_l], q2 = attns[2][n_l], q3 = attns[3][n_l];
        a0[0] = fmaf(q0, v0, a0[0]); a1[0] = fmaf(q0, v1, a1[0]);
        a0[1] = fmaf(q1, v0, a0[1]); a1[1] = fmaf(q1, v1, a1[1]);
        a0[2] = fmaf(q2, v0, a0[2]); a1[2] = fmaf(q2, v1, a1[2]);
        a0[3] = fmaf(q3, v0, a0[3]); a1[3] = fmaf(q3, v1, a1[3]);
    }
    __syncthreads();
    if (h == 0) {
        #pragma unroll
        for (int k = 0; k < K_; ++k) { upd_s[k][c] = a0[k]; upd_s[k][c + 1] = a1[k]; }
    }
    __syncthreads();
    if (h == 1) {
        #pragma unroll
        for (int k = 0; k < K_; ++k) { upd_s[k][c] += a0[k]; upd_s[k][c + 1] += a1[k]; }
    }
    __syncthreads();
    #pragma unroll
    for (int k = 0; k < K_; ++k)
        atomicAdd(&usum[((size_t)b * K_ + k) * 256 + tid], upd_s[k][tid]);
}

extern "C" void kernel_launch(void* const* d_in, const int* in_sizes, int n_in,
                              void* d_out, int out_size, void* d_ws, size_t ws_size,
                              hipStream_t stream) {
    (void)in_sizes; (void)n_in; (void)out_size; (void)ws_size;
    const float* x        = (const float*)d_in[0];
    const float* noise    = (const float*)d_in[1];
    const float* slot_mu  = (const float*)d_in[2];
    const float* slot_ls  = (const float*)d_in[3];
    const float* ln_in_g  = (const float*)d_in[4];
    const float* ln_in_b  = (const float*)d_in[5];
    const float* ln_sl_g  = (const float*)d_in[6];
    const float* ln_sl_b  = (const float*)d_in[7];
    const float* ln_mlp_g = (const float*)d_in[8];
    const float* ln_mlp_b = (const float*)d_in[9];
    const float* Wq = (const float*)d_in[10];
    const float* bq = (const float*)d_in[11];
    const float* Wk = (const float*)d_in[12];
    const float* bk = (const float*)d_in[13];
    const float* Wv = (const float*)d_in[14];
    const float* bv = (const float*)d_in[15];
    const float* Wu = (const float*)d_in[16];
    const float* bu = (const float*)d_in[17];
    const float* W1 = (const float*)d_in[18];
    const float* b1 = (const float*)d_in[19];
    const float* W2 = (const float*)d_in[20];
    const float* b2 = (const float*)d_in[21];
    const float* We1 = (const float*)d_in[22];
    const float* be1 = (const float*)d_in[23];
    const float* We2 = (const float*)d_in[24];
    const float* be2 = (const float*)d_in[25];
    float* out = (float*)d_out;

    char* ws = (char*)d_ws;
    unsigned short* xnb = (unsigned short*)ws;                  // 32 MiB
    float4* Wq4  = (float4*)(xnb + (size_t)NROWS * C_);
    float4* Wu4  = Wq4 + 16384;
    float4* W14  = Wu4 + 32768;
    float4* W24  = W14 + 32768;
    float4* We14 = W24 + 32768;
    float4* Wkq4 = We14 + 8192;
    float4* Wv4  = Wkq4 + 16384;
    float* slots = (float*)(Wv4 + 16384);
    float* qtbuf = slots + B_ * K_ * C_;
    float* qoffb = qtbuf + B_ * K_ * C_;
    float* usum  = qoffb + B_ * K_;                 // B*K*256 floats (64 KiB)
    float* denom = usum + B_ * K_ * C_;             // B*K floats

    prep_kernel<<<608, 256, 0, stream>>>(Wq, Wu, W1, W2, We1, Wk, Wv,
                                         Wq4, Wu4, W14, W24, We14, Wkq4, Wv4);
    xn_fused_kernel<<<dim3(64, 16), 256, 0, stream>>>(x, ln_in_g, ln_in_b, xnb);
    slot_init_q_kernel<<<B_ * K_, 1024, 0, stream>>>(noise, slot_mu, slot_ls,
                                                     ln_sl_g, ln_sl_b, Wq4, bq, Wkq4, bk,
                                                     slots, qtbuf, qoffb, usum, denom);
    for (int it = 0; it < ITERS_; ++it) {
        attn_fused_kernel<<<dim3(64, 16), 256, 0, stream>>>(qtbuf, qoffb, xnb,
                                                            usum, denom);
        if (it < ITERS_ - 1) {
            slot_update_q_kernel<<<B_ * K_, 1024, 0, stream>>>(
                slots, usum, denom, Wv4, bv, Wu4, bu, ln_mlp_g, ln_mlp_b,
                W14, b1, W24, b2, ln_sl_g, ln_sl_b, Wq4, bq, Wkq4, bk, qtbuf, qoffb);
        } else {
            slot_update_final_kernel<<<B_ * K_, 1024, 0, stream>>>(
                slots, usum, denom, Wv4, bv, Wu4, bu, ln_mlp_g, ln_mlp_b,
                W14, b1, W24, b2, We14, be1, We2, be2, out);
        }
    }
}

// Round 3
// 306.980 us; speedup vs baseline: 1.0485x; 1.0485x over previous
//
#include <hip/hip_runtime.h>
#include <math.h>

#define B_    16
#define C_    256
#define NPIX  4096      // H*W
#define K_    4
#define HID_  512
#define ITERS_ 3
#define NROWS (B_*NPIX) // 65536
#define EPS_  1e-8f

__device__ __forceinline__ float gelu_f(float x) {
    return 0.5f * x * (1.0f + erff(x * 0.70710678118654752f));
}

__device__ __forceinline__ unsigned short f2bf(float x) {
    union { float f; unsigned u; } v; v.f = x;
    unsigned r = v.u + 0x7fffu + ((v.u >> 16) & 1u);   // round-nearest-even
    return (unsigned short)(r >> 16);
}
__device__ __forceinline__ float bflo(unsigned u) {
    union { unsigned u; float f; } v; v.u = u << 16; return v.f;
}
__device__ __forceinline__ float bfhi(unsigned u) {
    union { unsigned u; float f; } v; v.u = u & 0xffff0000u; return v.f;
}
__device__ __forceinline__ float4 shfl_xor4(float4 v, int m) {
    v.x = __shfl_xor(v.x, m); v.y = __shfl_xor(v.y, m);
    v.z = __shfl_xor(v.z, m); v.w = __shfl_xor(v.w, m);
    return v;
}
__device__ __forceinline__ void fma4(float4& a, const float4 w, const float4 s) {
    a.x = fmaf(w.x, s.x, a.x); a.y = fmaf(w.y, s.y, a.y);
    a.z = fmaf(w.z, s.z, a.z); a.w = fmaf(w.w, s.w, a.w);
}
__device__ __forceinline__ float hsum4(const float4 a) {
    return (a.x + a.y) + (a.z + a.w);
}

// 1024-thread block: reduce a 256-wide pair held by q==0 threads (tid<256).
// wave-shfl + 4 partials: 2 barriers instead of 10.
__device__ __forceinline__ void redpair256(float a, float b, int tid, int q,
                                           float* r8, float& o1, float& o2) {
    if (q == 0) {
        #pragma unroll
        for (int m = 1; m <= 32; m <<= 1) { a += __shfl_xor(a, m); b += __shfl_xor(b, m); }
        if ((tid & 63) == 0) { r8[(tid >> 6) * 2] = a; r8[(tid >> 6) * 2 + 1] = b; }
    }
    __syncthreads();
    o1 = r8[0] + r8[2] + r8[4] + r8[6];
    o2 = r8[1] + r8[3] + r8[5] + r8[7];
    __syncthreads();
}

// ---------------- prep: packed + composed weights ----------------
// WuC4[c4][d], c4 in [0,64): {Wu[d][4c4..]}        (left half: input = prev)
//              c4 in [64,128): {Wuv[d][4(c4-64)..]} (Wuv = Wu_right . Wv; input = u')
// W14[c4][h]  = {W1[h][4c4..]}
// W24[h4][d]  = {W2[d][4h4..]}
// We14[c4][e] = {We1[e][4c4..]}
// Wqk4[c4][d] = {Wqk[d][4c4..]},  Wqk = Wk^T . Wq
// bv2  = Wu_right . bv ; bqk = Wk^T . bq ; wqoff[c] = (Wq^T bk)[c] ; wqoff[256] = bq.bk
__global__ __launch_bounds__(256) void prep_pack_kernel(
    const float* __restrict__ Wu, const float* __restrict__ W1,
    const float* __restrict__ W2, const float* __restrict__ We1,
    const float* __restrict__ Wq, const float* __restrict__ bk,
    const float* __restrict__ bq,
    float4* __restrict__ WuC4, float4* __restrict__ W14,
    float4* __restrict__ W24, float4* __restrict__ We14,
    float* __restrict__ wqoff) {
    __shared__ float r4[4];
    int i = blockIdx.x * 256 + threadIdx.x;
    if (blockIdx.x == 352) {        // wqoff + bqoff
        int c = threadIdx.x;
        float s = 0.f;
        for (int dd = 0; dd < 256; ++dd) s = fmaf(Wq[dd * 256 + c], bk[dd], s);
        wqoff[c] = s;
        float p = bq[c] * bk[c];
        #pragma unroll
        for (int m = 1; m <= 32; m <<= 1) p += __shfl_xor(p, m);
        if ((c & 63) == 0) r4[c >> 6] = p;
        __syncthreads();
        if (c == 0) wqoff[256] = r4[0] + r4[1] + r4[2] + r4[3];
        return;
    }
    if (i < 16384) {
        int c4 = i >> 8, dd = i & 255;
        WuC4[i] = *(const float4*)&Wu[dd * 512 + c4 * 4];      // left half only
    } else if (i < 49152) {
        int j = i - 16384; int c4 = j >> 9, h = j & 511;
        W14[j] = *(const float4*)&W1[h * 256 + c4 * 4];
    } else if (i < 81920) {
        int j = i - 49152; int h4 = j >> 8, dd = j & 255;
        W24[j] = *(const float4*)&W2[dd * 512 + h4 * 4];
    } else {
        int j = i - 81920; int c4 = j >> 7, e = j & 127;
        We14[j] = *(const float4*)&We1[e * 256 + c4 * 4];
    }
}

// one block per output row d; computes Wuv[d][*], Wqk[d][*], bv2[d], bqk[d]
__global__ __launch_bounds__(256) void prep_compose_kernel(
    const float* __restrict__ Wu, const float* __restrict__ Wv,
    const float* __restrict__ Wk, const float* __restrict__ Wq,
    const float* __restrict__ bv, const float* __restrict__ bq,
    float4* __restrict__ WuC4, float4* __restrict__ Wqk4,
    float* __restrict__ bv2, float* __restrict__ bqk) {
    __shared__ float wur[256], wkc[256];
    __shared__ float ldsA[256], ldsB[256];
    __shared__ float r1[4], r2[4];
    const int d = blockIdx.x, c = threadIdx.x;
    wur[c] = Wu[d * 512 + 256 + c];     // Wu_right row d
    wkc[c] = Wk[c * 256 + d];           // Wk column d
    __syncthreads();
    float a = 0.f, b = 0.f;
    #pragma unroll 4
    for (int e = 0; e < 256; ++e) {
        a = fmaf(wur[e], Wv[e * 256 + c], a);   // Wuv[d][c]
        b = fmaf(wkc[e], Wq[e * 256 + c], b);   // Wqk[d][c]
    }
    ldsA[c] = a; ldsB[c] = b;
    float p1 = wur[c] * bv[c], p2 = wkc[c] * bq[c];
    #pragma unroll
    for (int m = 1; m <= 32; m <<= 1) { p1 += __shfl_xor(p1, m); p2 += __shfl_xor(p2, m); }
    if ((c & 63) == 0) { r1[c >> 6] = p1; r2[c >> 6] = p2; }
    __syncthreads();
    if (c < 64) {
        float4 qa = { ldsA[4 * c], ldsA[4 * c + 1], ldsA[4 * c + 2], ldsA[4 * c + 3] };
        float4 qb = { ldsB[4 * c], ldsB[4 * c + 1], ldsB[4 * c + 2], ldsB[4 * c + 3] };
        WuC4[(64 + c) * 256 + d] = qa;
        Wqk4[c * 256 + d] = qb;
    }
    if (c == 0) {
        bv2[d] = r1[0] + r1[1] + r1[2] + r1[3];
        bqk[d] = r2[0] + r2[1] + r2[2] + r2[3];
    }
}

// ---------------- fused LN(+stats) + transpose + bf16 convert, single x pass ----------------
__global__ __launch_bounds__(256) void xn_fused_kernel(
    const float* __restrict__ x, const float* __restrict__ g, const float* __restrict__ bta,
    unsigned short* __restrict__ xnb) {
    __shared__ float tile[256][65];
    __shared__ float sg[256], sb[256];
    __shared__ float red1[256], red2[256];
    __shared__ float smean[64], srstd[64];
    const int tid = threadIdx.x;
    const int nt = blockIdx.x << 6, b = blockIdx.y;

    sg[tid] = g[tid]; sb[tid] = bta[tid];
    #pragma unroll
    for (int r = 0; r < 64; ++r) {
        int idx = tid + (r << 8);
        int c_l = idx >> 6, n_l = idx & 63;
        tile[c_l][n_l] = x[(size_t)(b * C_ + c_l) * NPIX + nt + n_l];
    }
    __syncthreads();
    {
        int cq = tid >> 6, n_l = tid & 63;
        float s = 0.f, s2 = 0.f;
        #pragma unroll 8
        for (int c = cq * 64; c < cq * 64 + 64; ++c) {
            float v = tile[c][n_l];
            s += v; s2 += v * v;
        }
        red1[tid] = s; red2[tid] = s2;
    }
    __syncthreads();
    if (tid < 64) {
        float s  = red1[tid] + red1[tid + 64] + red1[tid + 128] + red1[tid + 192];
        float s2 = red2[tid] + red2[tid + 64] + red2[tid + 128] + red2[tid + 192];
        float m = s * (1.0f / C_);
        smean[tid] = m;
        srstd[tid] = rsqrtf(s2 * (1.0f / C_) - m * m + 1e-5f);
    }
    __syncthreads();
    #pragma unroll
    for (int r = 0; r < 32; ++r) {
        int idx = tid + (r << 8);
        int n_l = idx >> 7, cp = idx & 127;
        int c0 = cp << 1;
        float mn = smean[n_l], rs = srstd[n_l];
        float v0 = (tile[c0][n_l] - mn) * rs * sg[c0] + sb[c0];
        float v1 = (tile[c0 + 1][n_l] - mn) * rs * sg[c0 + 1] + sb[c0 + 1];
        ushort2 o; o.x = f2bf(v0); o.y = f2bf(v1);
        *reinterpret_cast<ushort2*>(&xnb[((size_t)(b * NPIX + nt + n_l)) * C_ + c0]) = o;
    }
}

// ---------------- slot kernels: 1024 threads, K split 4 ways (q = tid>>8) ----------------

// LN + qt = Wqk.snorm + bqk ; qoff = snorm.wqoff + bqoff   (single composed matvec)
__device__ __forceinline__ void ln_qt_1024(
    float v, int tid, int d, int q, int r,
    const float* __restrict__ g_sl, const float* __restrict__ b_sl,
    const float4* __restrict__ Wqk4, const float* __restrict__ bqk,
    const float* __restrict__ wqoff,
    float* __restrict__ qtbuf, float* __restrict__ qoffbuf,
    float* snorm, float* pq, float* r8) {
    float a = (q == 0) ? v : 0.f;
    float sm, s2;
    redpair256(a, a * v, tid, q, r8, sm, s2);
    if (q == 0) {
        float m = sm * (1.f / C_);
        float rs = rsqrtf(s2 * (1.f / C_) - m * m + 1e-5f);
        snorm[d] = (v - m) * rs * g_sl[d] + b_sl[d];
    }
    __syncthreads();
    // qt matvec (quarter over c)
    {
        const float4* sn4 = (const float4*)snorm;
        float4 a0 = {0,0,0,0}, a1 = {0,0,0,0};
        int c4b = q << 4;
        #pragma unroll
        for (int i = 0; i < 16; i += 2) {
            fma4(a0, Wqk4[(c4b + i) * 256 + d], sn4[c4b + i]);
            fma4(a1, Wqk4[(c4b + i + 1) * 256 + d], sn4[c4b + i + 1]);
        }
        pq[q * 256 + d] = hsum4(a0) + hsum4(a1);
    }
    // qoff dot (rides on redpair barriers, which also cover pq)
    float p = (q == 0) ? snorm[d] * wqoff[d] : 0.f;
    float qo, dum;
    redpair256(p, 0.f, tid, q, r8, qo, dum);
    if (tid == 0) qoffbuf[r] = qo + wqoff[256];
    if (q == 0)
        qtbuf[r * C_ + d] = pq[d] + pq[256 + d] + pq[512 + d] + pq[768 + d] + bqk[d];
}

__global__ __launch_bounds__(1024) void slot_init_q_kernel(
    const float* __restrict__ noise, const float* __restrict__ mu,
    const float* __restrict__ log_sigma,
    const float* __restrict__ g_sl, const float* __restrict__ b_sl,
    const float4* __restrict__ Wqk4, const float* __restrict__ bqk,
    const float* __restrict__ wqoff,
    float* __restrict__ slots, float* __restrict__ qtbuf, float* __restrict__ qoffbuf,
    float* __restrict__ usum, float* __restrict__ denom) {
    __shared__ __align__(16) float snorm[256];
    __shared__ float pq[1024];
    __shared__ float r8[8];
    int tid = threadIdx.x;
    int d = tid & 255, q = tid >> 8;
    int r = blockIdx.x;
    float v = 0.f;
    if (q == 0) {
        v = mu[d] + expf(log_sigma[d]) * noise[r * C_ + d];
        slots[r * C_ + d] = v;
        usum[r * C_ + d] = 0.f;          // zero accumulators for first attn pass
    }
    if (tid == 0) denom[r] = 0.f;
    ln_qt_1024(v, tid, d, q, r, g_sl, b_sl, Wqk4, bqk, wqoff,
               qtbuf, qoffbuf, snorm, pq, r8);
}

// slot update core; returns ov (valid for q==0 threads)
__device__ __forceinline__ float slot_update_body(
    int tid, int d, int q, int r, const float* __restrict__ slots,
    float* __restrict__ usum, float* __restrict__ denom,
    const float* __restrict__ bv2,
    const float4* __restrict__ WuC4, const float* __restrict__ bu,
    const float* __restrict__ g_mlp, const float* __restrict__ b_mlp,
    const float4* __restrict__ W14, const float* __restrict__ b1,
    const float4* __restrict__ W24, const float* __restrict__ b2,
    float* comb, float* pq, float* mrow, float* hrow,
    float* r8, float* s_denom, float* s_scale) {
    // phase 0: read accumulated u'' + denom; re-zero for next iter
    float uv = 0.f, prev = 0.f;
    if (q == 0) {
        uv = usum[r * C_ + d];
        usum[r * C_ + d] = 0.f;
        prev = slots[r * C_ + d];
    }
    if (tid == 0) {
        float dv = denom[r];
        *s_denom = dv + EPS_;
        *s_scale = dv / (dv + EPS_);
        denom[r] = 0.f;
    }
    __syncthreads();
    if (q == 0) {
        comb[d] = prev;
        comb[256 + d] = uv / *s_denom;           // u'
    }
    __syncthreads();
    // phase 1: composed [Wu_left | Wuv] (K=512), quarter = 32 c4
    const float4* cb4 = (const float4*)comb;
    {
        float4 a0 = {0,0,0,0}, a1 = {0,0,0,0}, a2 = {0,0,0,0}, a3 = {0,0,0,0};
        int c4b = q << 5;
        #pragma unroll
        for (int i = 0; i < 32; i += 4) {
            float4 w0 = WuC4[(c4b + i + 0) * 256 + d];
            float4 w1 = WuC4[(c4b + i + 1) * 256 + d];
            float4 w2 = WuC4[(c4b + i + 2) * 256 + d];
            float4 w3 = WuC4[(c4b + i + 3) * 256 + d];
            fma4(a0, w0, cb4[c4b + i + 0]); fma4(a1, w1, cb4[c4b + i + 1]);
            fma4(a2, w2, cb4[c4b + i + 2]); fma4(a3, w3, cb4[c4b + i + 3]);
        }
        pq[q * 256 + d] = (hsum4(a0) + hsum4(a1)) + (hsum4(a2) + hsum4(a3));
    }
    __syncthreads();
    float nv = 0.f, aa = 0.f;
    if (q == 0) {
        nv = pq[d] + pq[256 + d] + pq[512 + d] + pq[768 + d]
           + bu[d] + prev + (*s_scale) * bv2[d];
        aa = nv;
    }
    float sm, s2;
    redpair256(aa, aa * nv, tid, q, r8, sm, s2);
    if (q == 0) {
        float m = sm * (1.f / C_);
        float rs = rsqrtf(s2 * (1.f / C_) - m * m + 1e-5f);
        mrow[d] = (nv - m) * rs * g_mlp[d] + b_mlp[d];
    }
    __syncthreads();
    // phase 2: W1 (K=256 -> 512 outputs), halves (h2 = tid>>9)
    const float4* m4 = (const float4*)mrow;
    {
        int j = tid & 511, h2 = tid >> 9;
        float4 a0 = {0,0,0,0}, a1 = {0,0,0,0};
        int c4b = h2 << 5;
        #pragma unroll
        for (int i = 0; i < 32; i += 2) {
            float4 w0 = W14[(c4b + i + 0) * 512 + j];
            float4 w1 = W14[(c4b + i + 1) * 512 + j];
            fma4(a0, w0, m4[c4b + i + 0]); fma4(a1, w1, m4[c4b + i + 1]);
        }
        pq[h2 * 512 + j] = hsum4(a0) + hsum4(a1);
    }
    __syncthreads();
    if (tid < 512) hrow[tid] = gelu_f(pq[tid] + pq[512 + tid] + b1[tid]);
    __syncthreads();
    // phase 3: W2 (K=512)
    const float4* h4 = (const float4*)hrow;
    {
        float4 a0 = {0,0,0,0}, a1 = {0,0,0,0}, a2 = {0,0,0,0}, a3 = {0,0,0,0};
        int h4b = q << 5;
        #pragma unroll
        for (int i = 0; i < 32; i += 4) {
            float4 w0 = W24[(h4b + i + 0) * 256 + d];
            float4 w1 = W24[(h4b + i + 1) * 256 + d];
            float4 w2 = W24[(h4b + i + 2) * 256 + d];
            float4 w3 = W24[(h4b + i + 3) * 256 + d];
            fma4(a0, w0, h4[h4b + i + 0]); fma4(a1, w1, h4[h4b + i + 1]);
            fma4(a2, w2, h4[h4b + i + 2]); fma4(a3, w3, h4[h4b + i + 3]);
        }
        pq[q * 256 + d] = (hsum4(a0) + hsum4(a1)) + (hsum4(a2) + hsum4(a3));
    }
    __syncthreads();
    float ov = 0.f;
    if (q == 0)
        ov = nv + pq[d] + pq[256 + d] + pq[512 + d] + pq[768 + d] + b2[d];
    return ov;
}

__global__ __launch_bounds__(1024) void slot_update_q_kernel(
    float* __restrict__ slots, float* __restrict__ usum, float* __restrict__ denom,
    const float* __restrict__ bv2,
    const float4* __restrict__ WuC4, const float* __restrict__ bu,
    const float* __restrict__ g_mlp, const float* __restrict__ b_mlp,
    const float4* __restrict__ W14, const float* __restrict__ b1,
    const float4* __restrict__ W24, const float* __restrict__ b2,
    const float* __restrict__ g_sl, const float* __restrict__ b_sl,
    const float4* __restrict__ Wqk4, const float* __restrict__ bqk,
    const float* __restrict__ wqoff,
    float* __restrict__ qtbuf, float* __restrict__ qoffbuf) {
    __shared__ __align__(16) float comb[512];
    __shared__ __align__(16) float mrow[256];
    __shared__ __align__(16) float hrow[512];
    __shared__ float pq[1024];
    __shared__ float r8[8];
    __shared__ float s_denom, s_scale;
    int tid = threadIdx.x;
    int d = tid & 255, q = tid >> 8;
    int r = blockIdx.x;
    float ov = slot_update_body(tid, d, q, r, slots, usum, denom, bv2, WuC4, bu,
                                g_mlp, b_mlp, W14, b1, W24, b2,
                                comb, pq, mrow, hrow, r8, &s_denom, &s_scale);
    if (q == 0) slots[r * C_ + d] = ov;
    ln_qt_1024(ov, tid, d, q, r, g_sl, b_sl, Wqk4, bqk, wqoff,
               qtbuf, qoffbuf, mrow, pq, r8);
}

__global__ __launch_bounds__(1024) void slot_update_final_kernel(
    float* __restrict__ slots, float* __restrict__ usum, float* __restrict__ denom,
    const float* __restrict__ bv2,
    const float4* __restrict__ WuC4, const float* __restrict__ bu,
    const float* __restrict__ g_mlp, const float* __restrict__ b_mlp,
    const float4* __restrict__ W14, const float* __restrict__ b1,
    const float4* __restrict__ W24, const float* __restrict__ b2,
    const float4* __restrict__ We14, const float* __restrict__ be1,
    const float* __restrict__ We2, const float* __restrict__ be2,
    float* __restrict__ out) {
    __shared__ __align__(16) float comb[512];
    __shared__ __align__(16) float mrow[256];
    __shared__ __align__(16) float hrow[512];
    __shared__ float pq[1024];
    __shared__ float r8[8];
    __shared__ float s_denom, s_scale;
    __shared__ float erow[128];
    int tid = threadIdx.x;
    int d = tid & 255, q = tid >> 8;
    int r = blockIdx.x;
    float ov = slot_update_body(tid, d, q, r, slots, usum, denom, bv2, WuC4, bu,
                                g_mlp, b_mlp, W14, b1, W24, b2,
                                comb, pq, mrow, hrow, r8, &s_denom, &s_scale);
    if (q == 0) {
        out[r * C_ + d] = ov;
        mrow[d] = ov;
    }
    __syncthreads();
    // We1: 128 outputs, 8-way K split (o8 = tid>>7, 8 c4 each)
    const float4* m4 = (const float4*)mrow;
    {
        int e = tid & 127, o8 = tid >> 7;
        float4 a0 = {0,0,0,0}, a1 = {0,0,0,0};
        int c4b = o8 << 3;
        #pragma unroll
        for (int i = 0; i < 8; i += 2) {
            fma4(a0, We14[(c4b + i) * 128 + e], m4[c4b + i]);
            fma4(a1, We14[(c4b + i + 1) * 128 + e], m4[c4b + i + 1]);
        }
        pq[o8 * 128 + e] = hsum4(a0) + hsum4(a1);
    }
    __syncthreads();
    if (tid < 128) {
        float s = 0.f;
        #pragma unroll
        for (int o = 0; o < 8; ++o) s += pq[o * 128 + tid];
        erow[tid] = gelu_f(s + be1[tid]);
    }
    __syncthreads();
    if (tid < 64) {
        float p = We2[tid] * erow[tid] + We2[tid + 64] * erow[tid + 64];
        #pragma unroll
        for (int m = 1; m <= 32; m <<= 1) p += __shfl_xor(p, m);
        if (tid == 0) out[B_ * K_ * C_ + r] = 1.0f / (1.0f + expf(-(p + be2[0])));
    }
}

// ---------------- fused attention: reads xnb directly (no k/v materialized) ----------------
// logits = qt.xn + qoff; u'' accumulated directly into usum via device-scope atomics
__global__ __launch_bounds__(256) void attn_fused_kernel(
    const float* __restrict__ qtbuf, const float* __restrict__ qoffbuf,
    const unsigned short* __restrict__ xnb,
    float* __restrict__ usum, float* __restrict__ denom) {
    __shared__ float4 qT[264];
    __shared__ float attns[K_][64];
    __shared__ float upd_s[K_][256];
    __shared__ float asw[4][4];
    __shared__ float4 qo_s;

    const int tid = threadIdx.x;
    const int b = blockIdx.y;
    const int chunk = blockIdx.x;
    const int n0 = chunk << 6;
    const int wave = tid >> 6, lane = tid & 63;

    {
        int c = tid;
        float4 qv;
        qv.x = qtbuf[b * 1024 + c];
        qv.y = qtbuf[b * 1024 + 256 + c];
        qv.z = qtbuf[b * 1024 + 512 + c];
        qv.w = qtbuf[b * 1024 + 768 + c];
        qT[c + (c >> 5)] = qv;
        if (tid == 0) qo_s = *(const float4*)&qoffbuf[b * 4];
    }
    __syncthreads();

    const int cpart = tid & 7;
    const int npair = tid >> 3;
    const int c0 = cpart << 5;
    float4 acc0 = {0.f, 0.f, 0.f, 0.f}, acc1 = {0.f, 0.f, 0.f, 0.f};
    const unsigned short* kbase = xnb + ((size_t)b * NPIX + n0 + npair * 2) * C_ + c0;
    #pragma unroll
    for (int j = 0; j < 4; ++j) {
        uint4 k0 = *reinterpret_cast<const uint4*>(kbase + j * 8);
        uint4 k1 = *reinterpret_cast<const uint4*>(kbase + C_ + j * 8);
        const unsigned kw0[4] = {k0.x, k0.y, k0.z, k0.w};
        const unsigned kw1[4] = {k1.x, k1.y, k1.z, k1.w};
        #pragma unroll
        for (int jj = 0; jj < 4; ++jj) {
            int cidx = c0 + j * 8 + jj * 2 + cpart;
            float4 qa = qT[cidx];
            float4 qb = qT[cidx + 1];
            float f00 = bflo(kw0[jj]), f01 = bfhi(kw0[jj]);
            float f10 = bflo(kw1[jj]), f11 = bfhi(kw1[jj]);
            acc0.x += f00 * qa.x + f01 * qb.x;  acc0.y += f00 * qa.y + f01 * qb.y;
            acc0.z += f00 * qa.z + f01 * qb.z;  acc0.w += f00 * qa.w + f01 * qb.w;
            acc1.x += f10 * qa.x + f11 * qb.x;  acc1.y += f10 * qa.y + f11 * qb.y;
            acc1.z += f10 * qa.z + f11 * qb.z;  acc1.w += f10 * qa.w + f11 * qb.w;
        }
    }
    #pragma unroll
    for (int m = 1; m <= 4; m <<= 1) {
        acc0 = acc0 + shfl_xor4(acc0, m);
        acc1 = acc1 + shfl_xor4(acc1, m);
    }
    float4 w0, w1;
    {
        float4 l = (acc0 + qo_s) * 0.0625f;
        float mx = fmaxf(fmaxf(l.x, l.y), fmaxf(l.z, l.w));
        w0.x = expf(l.x - mx); w0.y = expf(l.y - mx);
        w0.z = expf(l.z - mx); w0.w = expf(l.w - mx);
        float inv = 1.0f / (w0.x + w0.y + w0.z + w0.w);
        w0 = w0 * inv;
        l = (acc1 + qo_s) * 0.0625f;
        mx = fmaxf(fmaxf(l.x, l.y), fmaxf(l.z, l.w));
        w1.x = expf(l.x - mx); w1.y = expf(l.y - mx);
        w1.z = expf(l.z - mx); w1.w = expf(l.w - mx);
        inv = 1.0f / (w1.x + w1.y + w1.z + w1.w);
        w1 = w1 * inv;
    }
    if (cpart == 0) {
        int n_l = npair * 2;
        attns[0][n_l] = w0.x; attns[1][n_l] = w0.y; attns[2][n_l] = w0.z; attns[3][n_l] = w0.w;
        attns[0][n_l + 1] = w1.x; attns[1][n_l + 1] = w1.y;
        attns[2][n_l + 1] = w1.z; attns[3][n_l + 1] = w1.w;
    }
    float4 ws = w0 + w1;
    #pragma unroll
    for (int m = 8; m <= 32; m <<= 1) ws = ws + shfl_xor4(ws, m);
    if (lane == 0) {
        asw[wave][0] = ws.x; asw[wave][1] = ws.y; asw[wave][2] = ws.z; asw[wave][3] = ws.w;
    }
    __syncthreads();
    if (tid < 4)
        atomicAdd(&denom[b * 4 + tid],
                  asw[0][tid] + asw[1][tid] + asw[2][tid] + asw[3][tid]);

    const int h = wave >> 1;
    const int chalf = (wave & 1) << 7;
    const int c = chalf + lane * 2;
    float a0[K_] = {0.f, 0.f, 0.f, 0.f};
    float a1[K_] = {0.f, 0.f, 0.f, 0.f};
    const unsigned short* vbase = xnb + ((size_t)b * NPIX + n0 + h * 32) * C_ + c;
    #pragma unroll 4
    for (int nn = 0; nn < 32; ++nn) {
        unsigned vv = *reinterpret_cast<const unsigned*>(vbase + (size_t)nn * C_);
        float v0 = bflo(vv), v1 = bfhi(vv);
        int n_l = h * 32 + nn;
        float q0 = attns[0][n_l], q1 = attns[1][n_l], q2 = attns[2][n_l], q3 = attns[3][n_l];
        a0[0] = fmaf(q0, v0, a0[0]); a1[0] = fmaf(q0, v1, a1[0]);
        a0[1] = fmaf(q1, v0, a0[1]); a1[1] = fmaf(q1, v1, a1[1]);
        a0[2] = fmaf(q2, v0, a0[2]); a1[2] = fmaf(q2, v1, a1[2]);
        a0[3] = fmaf(q3, v0, a0[3]); a1[3] = fmaf(q3, v1, a1[3]);
    }
    __syncthreads();
    if (h == 0) {
        #pragma unroll
        for (int k = 0; k < K_; ++k) { upd_s[k][c] = a0[k]; upd_s[k][c + 1] = a1[k]; }
    }
    __syncthreads();
    if (h == 1) {
        #pragma unroll
        for (int k = 0; k < K_; ++k) { upd_s[k][c] += a0[k]; upd_s[k][c + 1] += a1[k]; }
    }
    __syncthreads();
    #pragma unroll
    for (int k = 0; k < K_; ++k)
        atomicAdd(&usum[((size_t)b * K_ + k) * 256 + tid], upd_s[k][tid]);
}

extern "C" void kernel_launch(void* const* d_in, const int* in_sizes, int n_in,
                              void* d_out, int out_size, void* d_ws, size_t ws_size,
                              hipStream_t stream) {
    (void)in_sizes; (void)n_in; (void)out_size; (void)ws_size;
    const float* x        = (const float*)d_in[0];
    const float* noise    = (const float*)d_in[1];
    const float* slot_mu  = (const float*)d_in[2];
    const float* slot_ls  = (const float*)d_in[3];
    const float* ln_in_g  = (const float*)d_in[4];
    const float* ln_in_b  = (const float*)d_in[5];
    const float* ln_sl_g  = (const float*)d_in[6];
    const float* ln_sl_b  = (const float*)d_in[7];
    const float* ln_mlp_g = (const float*)d_in[8];
    const float* ln_mlp_b = (const float*)d_in[9];
    const float* Wq = (const float*)d_in[10];
    const float* bq = (const float*)d_in[11];
    const float* Wk = (const float*)d_in[12];
    const float* bk = (const float*)d_in[13];
    const float* Wv = (const float*)d_in[14];
    const float* bv = (const float*)d_in[15];
    const float* Wu = (const float*)d_in[16];
    const float* bu = (const float*)d_in[17];
    const float* W1 = (const float*)d_in[18];
    const float* b1 = (const float*)d_in[19];
    const float* W2 = (const float*)d_in[20];
    const float* b2 = (const float*)d_in[21];
    const float* We1 = (const float*)d_in[22];
    const float* be1 = (const float*)d_in[23];
    const float* We2 = (const float*)d_in[24];
    const float* be2 = (const float*)d_in[25];
    float* out = (float*)d_out;

    char* ws = (char*)d_ws;
    unsigned short* xnb = (unsigned short*)ws;                  // 32 MiB
    float4* WuC4 = (float4*)(xnb + (size_t)NROWS * C_);         // 32768 f4
    float4* W14  = WuC4 + 32768;                                // 32768 f4
    float4* W24  = W14 + 32768;                                 // 32768 f4
    float4* We14 = W24 + 32768;                                 // 8192 f4
    float4* Wqk4 = We14 + 8192;                                 // 16384 f4
    float* bv2   = (float*)(Wqk4 + 16384);                      // 256
    float* bqk   = bv2 + 256;                                   // 256
    float* wqoff = bqk + 256;                                   // 257 (+pad)
    float* slots = wqoff + 260;                                 // 16384
    float* qtbuf = slots + B_ * K_ * C_;                        // 16384
    float* qoffb = qtbuf + B_ * K_ * C_;                        // 64
    float* usum  = qoffb + B_ * K_;                             // 16384
    float* denom = usum + B_ * K_ * C_;                         // 64

    prep_pack_kernel<<<353, 256, 0, stream>>>(Wu, W1, W2, We1, Wq, bk, bq,
                                              WuC4, W14, W24, We14, wqoff);
    prep_compose_kernel<<<256, 256, 0, stream>>>(Wu, Wv, Wk, Wq, bv, bq,
                                                 WuC4, Wqk4, bv2, bqk);
    xn_fused_kernel<<<dim3(64, 16), 256, 0, stream>>>(x, ln_in_g, ln_in_b, xnb);
    slot_init_q_kernel<<<B_ * K_, 1024, 0, stream>>>(noise, slot_mu, slot_ls,
                                                     ln_sl_g, ln_sl_b, Wqk4, bqk, wqoff,
                                                     slots, qtbuf, qoffb, usum, denom);
    for (int it = 0; it < ITERS_; ++it) {
        attn_fused_kernel<<<dim3(64, 16), 256, 0, stream>>>(qtbuf, qoffb, xnb,
                                                            usum, denom);
        if (it < ITERS_ - 1) {
            slot_update_q_kernel<<<B_ * K_, 1024, 0, stream>>>(
                slots, usum, denom, bv2, WuC4, bu, ln_mlp_g, ln_mlp_b,
                W14, b1, W24, b2, ln_sl_g, ln_sl_b, Wqk4, bqk, wqoff, qtbuf, qoffb);
        } else {
            slot_update_final_kernel<<<B_ * K_, 1024, 0, stream>>>(
                slots, usum, denom, bv2, WuC4, bu, ln_mlp_g, ln_mlp_b,
                W14, b1, W24, b2, We14, be1, We2, be2, out);
        }
    }
}

// Round 4
// 299.029 us; speedup vs baseline: 1.0764x; 1.0266x over previous
//
#include <hip/hip_runtime.h>
#include <math.h>

#define B_    16
#define C_    256
#define NPIX  4096      // H*W
#define K_    4
#define HID_  512
#define ITERS_ 3
#define NROWS (B_*NPIX) // 65536
#define EPS_  1e-8f

__device__ __forceinline__ float gelu_f(float x) {
    return 0.5f * x * (1.0f + erff(x * 0.70710678118654752f));
}

__device__ __forceinline__ unsigned short f2bf(float x) {
    union { float f; unsigned u; } v; v.f = x;
    unsigned r = v.u + 0x7fffu + ((v.u >> 16) & 1u);   // round-nearest-even
    return (unsigned short)(r >> 16);
}
__device__ __forceinline__ float bflo(unsigned u) {
    union { unsigned u; float f; } v; v.u = u << 16; return v.f;
}
__device__ __forceinline__ float bfhi(unsigned u) {
    union { unsigned u; float f; } v; v.u = u & 0xffff0000u; return v.f;
}
__device__ __forceinline__ float4 shfl_xor4(float4 v, int m) {
    v.x = __shfl_xor(v.x, m); v.y = __shfl_xor(v.y, m);
    v.z = __shfl_xor(v.z, m); v.w = __shfl_xor(v.w, m);
    return v;
}
__device__ __forceinline__ void fma4(float4& a, const float4 w, const float4 s) {
    a.x = fmaf(w.x, s.x, a.x); a.y = fmaf(w.y, s.y, a.y);
    a.z = fmaf(w.z, s.z, a.z); a.w = fmaf(w.w, s.w, a.w);
}
__device__ __forceinline__ float hsum4(const float4 a) {
    return (a.x + a.y) + (a.z + a.w);
}

// 256-thread block (4 waves): reduce (a,b) held by all threads.
// NOTE: no trailing sync — caller must sync before reusing r8.
__device__ __forceinline__ void redpair256t(float a, float b, int t, float* r8,
                                            float& o1, float& o2) {
    #pragma unroll
    for (int m = 1; m <= 32; m <<= 1) { a += __shfl_xor(a, m); b += __shfl_xor(b, m); }
    if ((t & 63) == 0) { r8[(t >> 6) * 2] = a; r8[(t >> 6) * 2 + 1] = b; }
    __syncthreads();
    o1 = r8[0] + r8[2] + r8[4] + r8[6];
    o2 = r8[1] + r8[3] + r8[5] + r8[7];
}

// ---------------- prep: packed + composed weights ----------------
// WuC4[c4][d], c4 in [0,64): {Wu[d][4c4..]}        (left half: input = prev)
//              c4 in [64,128): {Wuv[d][4(c4-64)..]} (Wuv = Wu_right . Wv; input = u')
// W14[c4][h]  = {W1[h][4c4..]}
// W24[h4][d]  = {W2[d][4h4..]}
// We14[c4][e] = {We1[e][4c4..]}
// Wqk4[c4][d] = {Wqk[d][4c4..]},  Wqk = Wk^T . Wq
// bv2  = Wu_right . bv ; bqk = Wk^T . bq ; wqoff[c] = (Wq^T bk)[c] ; wqoff[256] = bq.bk
__global__ __launch_bounds__(256) void prep_pack_kernel(
    const float* __restrict__ Wu, const float* __restrict__ W1,
    const float* __restrict__ W2, const float* __restrict__ We1,
    const float* __restrict__ Wq, const float* __restrict__ bk,
    const float* __restrict__ bq,
    float4* __restrict__ WuC4, float4* __restrict__ W14,
    float4* __restrict__ W24, float4* __restrict__ We14,
    float* __restrict__ wqoff) {
    __shared__ float r4[4];
    int i = blockIdx.x * 256 + threadIdx.x;
    if (blockIdx.x == 352) {        // wqoff + bqoff
        int c = threadIdx.x;
        float s = 0.f;
        for (int dd = 0; dd < 256; ++dd) s = fmaf(Wq[dd * 256 + c], bk[dd], s);
        wqoff[c] = s;
        float p = bq[c] * bk[c];
        #pragma unroll
        for (int m = 1; m <= 32; m <<= 1) p += __shfl_xor(p, m);
        if ((c & 63) == 0) r4[c >> 6] = p;
        __syncthreads();
        if (c == 0) wqoff[256] = r4[0] + r4[1] + r4[2] + r4[3];
        return;
    }
    if (i < 16384) {
        int c4 = i >> 8, dd = i & 255;
        WuC4[i] = *(const float4*)&Wu[dd * 512 + c4 * 4];      // left half only
    } else if (i < 49152) {
        int j = i - 16384; int c4 = j >> 9, h = j & 511;
        W14[j] = *(const float4*)&W1[h * 256 + c4 * 4];
    } else if (i < 81920) {
        int j = i - 49152; int h4 = j >> 8, dd = j & 255;
        W24[j] = *(const float4*)&W2[dd * 512 + h4 * 4];
    } else {
        int j = i - 81920; int c4 = j >> 7, e = j & 127;
        We14[j] = *(const float4*)&We1[e * 256 + c4 * 4];
    }
}

// one block per output row d; computes Wuv[d][*], Wqk[d][*], bv2[d], bqk[d]
__global__ __launch_bounds__(256) void prep_compose_kernel(
    const float* __restrict__ Wu, const float* __restrict__ Wv,
    const float* __restrict__ Wk, const float* __restrict__ Wq,
    const float* __restrict__ bv, const float* __restrict__ bq,
    float4* __restrict__ WuC4, float4* __restrict__ Wqk4,
    float* __restrict__ bv2, float* __restrict__ bqk) {
    __shared__ float wur[256], wkc[256];
    __shared__ float ldsA[256], ldsB[256];
    __shared__ float r1[4], r2[4];
    const int d = blockIdx.x, c = threadIdx.x;
    wur[c] = Wu[d * 512 + 256 + c];     // Wu_right row d
    wkc[c] = Wk[c * 256 + d];           // Wk column d
    __syncthreads();
    float a = 0.f, b = 0.f;
    #pragma unroll 4
    for (int e = 0; e < 256; ++e) {
        a = fmaf(wur[e], Wv[e * 256 + c], a);   // Wuv[d][c]
        b = fmaf(wkc[e], Wq[e * 256 + c], b);   // Wqk[d][c]
    }
    ldsA[c] = a; ldsB[c] = b;
    float p1 = wur[c] * bv[c], p2 = wkc[c] * bq[c];
    #pragma unroll
    for (int m = 1; m <= 32; m <<= 1) { p1 += __shfl_xor(p1, m); p2 += __shfl_xor(p2, m); }
    if ((c & 63) == 0) { r1[c >> 6] = p1; r2[c >> 6] = p2; }
    __syncthreads();
    if (c < 64) {
        float4 qa = { ldsA[4 * c], ldsA[4 * c + 1], ldsA[4 * c + 2], ldsA[4 * c + 3] };
        float4 qb = { ldsB[4 * c], ldsB[4 * c + 1], ldsB[4 * c + 2], ldsB[4 * c + 3] };
        WuC4[(64 + c) * 256 + d] = qa;
        Wqk4[c * 256 + d] = qb;
    }
    if (c == 0) {
        bv2[d] = r1[0] + r1[1] + r1[2] + r1[3];
        bqk[d] = r2[0] + r2[1] + r2[2] + r2[3];
    }
}

// ---------------- fused LN(+stats) + transpose + bf16 convert, single x pass ----------------
__global__ __launch_bounds__(256) void xn_fused_kernel(
    const float* __restrict__ x, const float* __restrict__ g, const float* __restrict__ bta,
    unsigned short* __restrict__ xnb) {
    __shared__ float tile[256][65];
    __shared__ float sg[256], sb[256];
    __shared__ float red1[256], red2[256];
    __shared__ float smean[64], srstd[64];
    const int tid = threadIdx.x;
    const int nt = blockIdx.x << 6, b = blockIdx.y;

    sg[tid] = g[tid]; sb[tid] = bta[tid];
    #pragma unroll
    for (int r = 0; r < 64; ++r) {
        int idx = tid + (r << 8);
        int c_l = idx >> 6, n_l = idx & 63;
        tile[c_l][n_l] = x[(size_t)(b * C_ + c_l) * NPIX + nt + n_l];
    }
    __syncthreads();
    {
        int cq = tid >> 6, n_l = tid & 63;
        float s = 0.f, s2 = 0.f;
        #pragma unroll 8
        for (int c = cq * 64; c < cq * 64 + 64; ++c) {
            float v = tile[c][n_l];
            s += v; s2 += v * v;
        }
        red1[tid] = s; red2[tid] = s2;
    }
    __syncthreads();
    if (tid < 64) {
        float s  = red1[tid] + red1[tid + 64] + red1[tid + 128] + red1[tid + 192];
        float s2 = red2[tid] + red2[tid + 64] + red2[tid + 128] + red2[tid + 192];
        float m = s * (1.0f / C_);
        smean[tid] = m;
        srstd[tid] = rsqrtf(s2 * (1.0f / C_) - m * m + 1e-5f);
    }
    __syncthreads();
    #pragma unroll
    for (int r = 0; r < 32; ++r) {
        int idx = tid + (r << 8);
        int n_l = idx >> 7, cp = idx & 127;
        int c0 = cp << 1;
        float mn = smean[n_l], rs = srstd[n_l];
        float v0 = (tile[c0][n_l] - mn) * rs * sg[c0] + sb[c0];
        float v1 = (tile[c0 + 1][n_l] - mn) * rs * sg[c0 + 1] + sb[c0 + 1];
        ushort2 o; o.x = f2bf(v0); o.y = f2bf(v1);
        *reinterpret_cast<ushort2*>(&xnb[((size_t)(b * NPIX + nt + n_l)) * C_ + c0]) = o;
    }
}

// ---------------- slot phase kernels: d-split grids, kernel-boundary sync ----------------

__global__ __launch_bounds__(256) void init_slots_kernel(
    const float* __restrict__ noise, const float* __restrict__ mu,
    const float* __restrict__ log_sigma,
    float* __restrict__ slots, float* __restrict__ usum, float* __restrict__ denom) {
    int t = threadIdx.x, r = blockIdx.x;
    float v = mu[t] + expf(log_sigma[t]) * noise[r * C_ + t];
    slots[r * C_ + t] = v;
    usum[r * C_ + t] = 0.f;
    if (t == 0) denom[r] = 0.f;
}

// LN_sl + qt = Wqk.snorm + bqk (d-tile), dq==0 block also computes qoff.
// grid (4, 64): dq = blockIdx.x, r = blockIdx.y. src = slots.
__global__ __launch_bounds__(256) void qt_kernel(
    const float* __restrict__ src,
    const float* __restrict__ g_sl, const float* __restrict__ b_sl,
    const float4* __restrict__ Wqk4, const float* __restrict__ bqk,
    const float* __restrict__ wqoff,
    float* __restrict__ qtbuf, float* __restrict__ qoffbuf) {
    __shared__ __align__(16) float snorm[256];
    __shared__ float pq[256];
    __shared__ float r8[8];
    const int t = threadIdx.x, dq = blockIdx.x, r = blockIdx.y;
    float v = src[r * C_ + t];
    float sm, s2;
    redpair256t(v, v * v, t, r8, sm, s2);
    float mean = sm * (1.f / C_);
    float rs = rsqrtf(s2 * (1.f / C_) - mean * mean + 1e-5f);
    snorm[t] = (v - mean) * rs * g_sl[t] + b_sl[t];
    __syncthreads();
    const float4* sn4 = (const float4*)snorm;
    const int dloc = t & 63, ks = t >> 6;
    const int d = dq * 64 + dloc;
    {
        float4 a0 = {0,0,0,0}, a1 = {0,0,0,0};
        int c4b = ks << 4;
        #pragma unroll
        for (int i = 0; i < 16; i += 2) {
            fma4(a0, Wqk4[(c4b + i) * 256 + d], sn4[c4b + i]);
            fma4(a1, Wqk4[(c4b + i + 1) * 256 + d], sn4[c4b + i + 1]);
        }
        pq[ks * 64 + dloc] = hsum4(a0) + hsum4(a1);
    }
    __syncthreads();
    if (t < 64) {
        float s = pq[t] + pq[64 + t] + pq[128 + t] + pq[192 + t];
        qtbuf[r * C_ + dq * 64 + t] = s + bqk[dq * 64 + t];
    }
    if (dq == 0) {
        float p = snorm[t] * wqoff[t];
        #pragma unroll
        for (int m = 1; m <= 32; m <<= 1) p += __shfl_xor(p, m);
        if ((t & 63) == 0) r8[t >> 6] = p;
        __syncthreads();
        if (t == 0) qoffbuf[r] = r8[0] + r8[1] + r8[2] + r8[3] + wqoff[256];
    }
}

// phase 1: nv = [Wu_left | Wuv].[prev; u'] + bu + prev + scale*bv2
// grid (8, 64): dq = blockIdx.x (32 d each), r = blockIdx.y
__global__ __launch_bounds__(256) void upd_wu_kernel(
    const float* __restrict__ slots, const float* __restrict__ usum,
    const float* __restrict__ denom,
    const float4* __restrict__ WuC4, const float* __restrict__ bu,
    const float* __restrict__ bv2,
    float* __restrict__ nvbuf) {
    __shared__ __align__(16) float comb[512];
    __shared__ float pq[256];
    __shared__ float sden, sscale;
    const int t = threadIdx.x, dq = blockIdx.x, r = blockIdx.y;
    if (t == 0) { float dv = denom[r]; sden = dv + EPS_; sscale = dv / (dv + EPS_); }
    comb[t] = slots[r * C_ + t];
    float uv = usum[r * C_ + t];
    __syncthreads();
    comb[256 + t] = uv / sden;
    __syncthreads();
    const float4* cb4 = (const float4*)comb;
    const int dloc = t & 31, ks = t >> 5;
    const int d = dq * 32 + dloc;
    {
        float4 a0 = {0,0,0,0}, a1 = {0,0,0,0};
        int c4b = ks << 4;
        #pragma unroll
        for (int i = 0; i < 16; i += 2) {
            fma4(a0, WuC4[(c4b + i) * 256 + d], cb4[c4b + i]);
            fma4(a1, WuC4[(c4b + i + 1) * 256 + d], cb4[c4b + i + 1]);
        }
        pq[ks * 32 + dloc] = hsum4(a0) + hsum4(a1);
    }
    __syncthreads();
    if (t < 32) {
        int dd = dq * 32 + t;
        float s = 0.f;
        #pragma unroll
        for (int i = 0; i < 8; ++i) s += pq[i * 32 + t];
        nvbuf[r * C_ + dd] = s + bu[dd] + comb[dd] + sscale * bv2[dd];
    }
}

// phase 2: redundant LN_mlp + W1 h-tile + gelu. hq==0 block re-zeroes usum/denom.
// grid (8, 64): hq = blockIdx.x (64 h each), r = blockIdx.y
__global__ __launch_bounds__(256) void upd_w1_kernel(
    const float* __restrict__ nvbuf,
    const float* __restrict__ g_mlp, const float* __restrict__ b_mlp,
    const float4* __restrict__ W14, const float* __restrict__ b1,
    float* __restrict__ hbuf, float* __restrict__ usum, float* __restrict__ denom) {
    __shared__ __align__(16) float mrow[256];
    __shared__ float pq[256];
    __shared__ float r8[8];
    const int t = threadIdx.x, hq = blockIdx.x, r = blockIdx.y;
    float nv = nvbuf[r * C_ + t];
    float sm, s2;
    redpair256t(nv, nv * nv, t, r8, sm, s2);
    float mean = sm * (1.f / C_);
    float rs = rsqrtf(s2 * (1.f / C_) - mean * mean + 1e-5f);
    mrow[t] = (nv - mean) * rs * g_mlp[t] + b_mlp[t];
    if (hq == 0) {                       // safe: upd_wu (prev kernel) already consumed
        usum[r * C_ + t] = 0.f;
        if (t == 0) denom[r] = 0.f;
    }
    __syncthreads();
    const float4* m4 = (const float4*)mrow;
    const int hloc = t & 63, ks = t >> 6;
    const int h = hq * 64 + hloc;
    {
        float4 a0 = {0,0,0,0}, a1 = {0,0,0,0};
        int c4b = ks << 4;
        #pragma unroll
        for (int i = 0; i < 16; i += 2) {
            fma4(a0, W14[(c4b + i) * 512 + h], m4[c4b + i]);
            fma4(a1, W14[(c4b + i + 1) * 512 + h], m4[c4b + i + 1]);
        }
        pq[ks * 64 + hloc] = hsum4(a0) + hsum4(a1);
    }
    __syncthreads();
    if (t < 64) {
        float s = pq[t] + pq[64 + t] + pq[128 + t] + pq[192 + t];
        hbuf[r * HID_ + hq * 64 + t] = gelu_f(s + b1[hq * 64 + t]);
    }
}

// phase 3: ov = nv + W2.h + b2 (d-tile). dst = slots (iters 0,1) or out (final).
// grid (8, 64): dq = blockIdx.x (32 d each), r = blockIdx.y
__global__ __launch_bounds__(256) void upd_w2_kernel(
    const float* __restrict__ nvbuf, const float* __restrict__ hbuf,
    const float4* __restrict__ W24, const float* __restrict__ b2,
    float* __restrict__ dst) {
    __shared__ __align__(16) float hrow[512];
    __shared__ float pq[256];
    const int t = threadIdx.x, dq = blockIdx.x, r = blockIdx.y;
    hrow[t] = hbuf[r * HID_ + t];
    hrow[256 + t] = hbuf[r * HID_ + 256 + t];
    __syncthreads();
    const float4* h4 = (const float4*)hrow;
    const int dloc = t & 31, ks = t >> 5;
    const int d = dq * 32 + dloc;
    {
        float4 a0 = {0,0,0,0}, a1 = {0,0,0,0};
        int h4b = ks << 4;
        #pragma unroll
        for (int i = 0; i < 16; i += 2) {
            fma4(a0, W24[(h4b + i) * 256 + d], h4[h4b + i]);
            fma4(a1, W24[(h4b + i + 1) * 256 + d], h4[h4b + i + 1]);
        }
        pq[ks * 32 + dloc] = hsum4(a0) + hsum4(a1);
    }
    __syncthreads();
    if (t < 32) {
        int dd = dq * 32 + t;
        float s = 0.f;
        #pragma unroll
        for (int i = 0; i < 8; ++i) s += pq[i * 32 + t];
        dst[r * C_ + dd] = nvbuf[r * C_ + dd] + s + b2[dd];
    }
}

// final head: e = gelu(We1.ov + be1); w = sigmoid(We2.e + be2). grid 64.
__global__ __launch_bounds__(256) void head_kernel(
    const float* __restrict__ ovbuf,
    const float4* __restrict__ We14, const float* __restrict__ be1,
    const float* __restrict__ We2, const float* __restrict__ be2,
    float* __restrict__ out) {
    __shared__ __align__(16) float mrow[256];
    __shared__ float pq[256];
    __shared__ float erow[128];
    __shared__ float r4[4];
    const int t = threadIdx.x, r = blockIdx.x;
    mrow[t] = ovbuf[r * C_ + t];
    __syncthreads();
    const float4* m4 = (const float4*)mrow;
    const int e = t & 127, o2 = t >> 7;
    {
        float4 a0 = {0,0,0,0}, a1 = {0,0,0,0};
        int c4b = o2 << 5;
        #pragma unroll
        for (int i = 0; i < 32; i += 2) {
            fma4(a0, We14[(c4b + i) * 128 + e], m4[c4b + i]);
            fma4(a1, We14[(c4b + i + 1) * 128 + e], m4[c4b + i + 1]);
        }
        pq[o2 * 128 + e] = hsum4(a0) + hsum4(a1);
    }
    __syncthreads();
    if (t < 128) erow[t] = gelu_f(pq[t] + pq[128 + t] + be1[t]);
    __syncthreads();
    if (t < 64) {
        float p = We2[t] * erow[t] + We2[t + 64] * erow[t + 64];
        #pragma unroll
        for (int m = 1; m <= 32; m <<= 1) p += __shfl_xor(p, m);
        if (t == 0) { r4[0] = p; }
    }
    __syncthreads();
    if (t == 0) out[B_ * K_ * C_ + r] = 1.0f / (1.0f + expf(-(r4[0] + be2[0])));
}

// ---------------- fused attention: reads xnb directly (no k/v materialized) ----------------
// logits = qt.xn + qoff; u'' accumulated directly into usum via device-scope atomics
__global__ __launch_bounds__(256) void attn_fused_kernel(
    const float* __restrict__ qtbuf, const float* __restrict__ qoffbuf,
    const unsigned short* __restrict__ xnb,
    float* __restrict__ usum, float* __restrict__ denom) {
    __shared__ float4 qT[264];
    __shared__ float attns[K_][64];
    __shared__ float upd_s[K_][256];
    __shared__ float asw[4][4];
    __shared__ float4 qo_s;

    const int tid = threadIdx.x;
    const int b = blockIdx.y;
    const int chunk = blockIdx.x;
    const int n0 = chunk << 6;
    const int wave = tid >> 6, lane = tid & 63;

    {
        int c = tid;
        float4 qv;
        qv.x = qtbuf[b * 1024 + c];
        qv.y = qtbuf[b * 1024 + 256 + c];
        qv.z = qtbuf[b * 1024 + 512 + c];
        qv.w = qtbuf[b * 1024 + 768 + c];
        qT[c + (c >> 5)] = qv;
        if (tid == 0) qo_s = *(const float4*)&qoffbuf[b * 4];
    }
    __syncthreads();

    const int cpart = tid & 7;
    const int npair = tid >> 3;
    const int c0 = cpart << 5;
    float4 acc0 = {0.f, 0.f, 0.f, 0.f}, acc1 = {0.f, 0.f, 0.f, 0.f};
    const unsigned short* kbase = xnb + ((size_t)b * NPIX + n0 + npair * 2) * C_ + c0;
    #pragma unroll
    for (int j = 0; j < 4; ++j) {
        uint4 k0 = *reinterpret_cast<const uint4*>(kbase + j * 8);
        uint4 k1 = *reinterpret_cast<const uint4*>(kbase + C_ + j * 8);
        const unsigned kw0[4] = {k0.x, k0.y, k0.z, k0.w};
        const unsigned kw1[4] = {k1.x, k1.y, k1.z, k1.w};
        #pragma unroll
        for (int jj = 0; jj < 4; ++jj) {
            int cidx = c0 + j * 8 + jj * 2 + cpart;
            float4 qa = qT[cidx];
            float4 qb = qT[cidx + 1];
            float f00 = bflo(kw0[jj]), f01 = bfhi(kw0[jj]);
            float f10 = bflo(kw1[jj]), f11 = bfhi(kw1[jj]);
            acc0.x += f00 * qa.x + f01 * qb.x;  acc0.y += f00 * qa.y + f01 * qb.y;
            acc0.z += f00 * qa.z + f01 * qb.z;  acc0.w += f00 * qa.w + f01 * qb.w;
            acc1.x += f10 * qa.x + f11 * qb.x;  acc1.y += f10 * qa.y + f11 * qb.y;
            acc1.z += f10 * qa.z + f11 * qb.z;  acc1.w += f10 * qa.w + f11 * qb.w;
        }
    }
    #pragma unroll
    for (int m = 1; m <= 4; m <<= 1) {
        acc0 = acc0 + shfl_xor4(acc0, m);
        acc1 = acc1 + shfl_xor4(acc1, m);
    }
    float4 w0, w1;
    {
        float4 l = (acc0 + qo_s) * 0.0625f;
        float mx = fmaxf(fmaxf(l.x, l.y), fmaxf(l.z, l.w));
        w0.x = expf(l.x - mx); w0.y = expf(l.y - mx);
        w0.z = expf(l.z - mx); w0.w = expf(l.w - mx);
        float inv = 1.0f / (w0.x + w0.y + w0.z + w0.w);
        w0 = w0 * inv;
        l = (acc1 + qo_s) * 0.0625f;
        mx = fmaxf(fmaxf(l.x, l.y), fmaxf(l.z, l.w));
        w1.x = expf(l.x - mx); w1.y = expf(l.y - mx);
        w1.z = expf(l.z - mx); w1.w = expf(l.w - mx);
        inv = 1.0f / (w1.x + w1.y + w1.z + w1.w);
        w1 = w1 * inv;
    }
    if (cpart == 0) {
        int n_l = npair * 2;
        attns[0][n_l] = w0.x; attns[1][n_l] = w0.y; attns[2][n_l] = w0.z; attns[3][n_l] = w0.w;
        attns[0][n_l + 1] = w1.x; attns[1][n_l + 1] = w1.y;
        attns[2][n_l + 1] = w1.z; attns[3][n_l + 1] = w1.w;
    }
    float4 ws = w0 + w1;
    #pragma unroll
    for (int m = 8; m <= 32; m <<= 1) ws = ws + shfl_xor4(ws, m);
    if (lane == 0) {
        asw[wave][0] = ws.x; asw[wave][1] = ws.y; asw[wave][2] = ws.z; asw[wave][3] = ws.w;
    }
    __syncthreads();
    if (tid < 4)
        atomicAdd(&denom[b * 4 + tid],
                  asw[0][tid] + asw[1][tid] + asw[2][tid] + asw[3][tid]);

    const int h = wave >> 1;
    const int chalf = (wave & 1) << 7;
    const int c = chalf + lane * 2;
    float a0[K_] = {0.f, 0.f, 0.f, 0.f};
    float a1[K_] = {0.f, 0.f, 0.f, 0.f};
    const unsigned short* vbase = xnb + ((size_t)b * NPIX + n0 + h * 32) * C_ + c;
    #pragma unroll 4
    for (int nn = 0; nn < 32; ++nn) {
        unsigned vv = *reinterpret_cast<const unsigned*>(vbase + (size_t)nn * C_);
        float v0 = bflo(vv), v1 = bfhi(vv);
        int n_l = h * 32 + nn;
        float q0 = attns[0][n_l], q1 = attns[1][n_l], q2 = attns[2][n_l], q3 = attns[3][n_l];
        a0[0] = fmaf(q0, v0, a0[0]); a1[0] = fmaf(q0, v1, a1[0]);
        a0[1] = fmaf(q1, v0, a0[1]); a1[1] = fmaf(q1, v1, a1[1]);
        a0[2] = fmaf(q2, v0, a0[2]); a1[2] = fmaf(q2, v1, a1[2]);
        a0[3] = fmaf(q3, v0, a0[3]); a1[3] = fmaf(q3, v1, a1[3]);
    }
    __syncthreads();
    if (h == 0) {
        #pragma unroll
        for (int k = 0; k < K_; ++k) { upd_s[k][c] = a0[k]; upd_s[k][c + 1] = a1[k]; }
    }
    __syncthreads();
    if (h == 1) {
        #pragma unroll
        for (int k = 0; k < K_; ++k) { upd_s[k][c] += a0[k]; upd_s[k][c + 1] += a1[k]; }
    }
    __syncthreads();
    #pragma unroll
    for (int k = 0; k < K_; ++k)
        atomicAdd(&usum[((size_t)b * K_ + k) * 256 + tid], upd_s[k][tid]);
}

extern "C" void kernel_launch(void* const* d_in, const int* in_sizes, int n_in,
                              void* d_out, int out_size, void* d_ws, size_t ws_size,
                              hipStream_t stream) {
    (void)in_sizes; (void)n_in; (void)out_size; (void)ws_size;
    const float* x        = (const float*)d_in[0];
    const float* noise    = (const float*)d_in[1];
    const float* slot_mu  = (const float*)d_in[2];
    const float* slot_ls  = (const float*)d_in[3];
    const float* ln_in_g  = (const float*)d_in[4];
    const float* ln_in_b  = (const float*)d_in[5];
    const float* ln_sl_g  = (const float*)d_in[6];
    const float* ln_sl_b  = (const float*)d_in[7];
    const float* ln_mlp_g = (const float*)d_in[8];
    const float* ln_mlp_b = (const float*)d_in[9];
    const float* Wq = (const float*)d_in[10];
    const float* bq = (const float*)d_in[11];
    const float* Wk = (const float*)d_in[12];
    const float* bk = (const float*)d_in[13];
    const float* Wv = (const float*)d_in[14];
    const float* bv = (const float*)d_in[15];
    const float* Wu = (const float*)d_in[16];
    const float* bu = (const float*)d_in[17];
    const float* W1 = (const float*)d_in[18];
    const float* b1 = (const float*)d_in[19];
    const float* W2 = (const float*)d_in[20];
    const float* b2 = (const float*)d_in[21];
    const float* We1 = (const float*)d_in[22];
    const float* be1 = (const float*)d_in[23];
    const float* We2 = (const float*)d_in[24];
    const float* be2 = (const float*)d_in[25];
    float* out = (float*)d_out;

    char* ws = (char*)d_ws;
    unsigned short* xnb = (unsigned short*)ws;                  // 32 MiB
    float4* WuC4 = (float4*)(xnb + (size_t)NROWS * C_);         // 32768 f4
    float4* W14  = WuC4 + 32768;                                // 32768 f4
    float4* W24  = W14 + 32768;                                 // 32768 f4
    float4* We14 = W24 + 32768;                                 // 8192 f4
    float4* Wqk4 = We14 + 8192;                                 // 16384 f4
    float* bv2   = (float*)(Wqk4 + 16384);                      // 256
    float* bqk   = bv2 + 256;                                   // 256
    float* wqoff = bqk + 256;                                   // 257 (+pad)
    float* slots = wqoff + 260;                                 // 16384
    float* qtbuf = slots + B_ * K_ * C_;                        // 16384
    float* qoffb = qtbuf + B_ * K_ * C_;                        // 64
    float* usum  = qoffb + B_ * K_;                             // 16384
    float* denom = usum + B_ * K_ * C_;                         // 64
    float* nvbuf = denom + B_ * K_;                             // 16384
    float* hbuf  = nvbuf + B_ * K_ * C_;                        // 32768

    prep_pack_kernel<<<353, 256, 0, stream>>>(Wu, W1, W2, We1, Wq, bk, bq,
                                              WuC4, W14, W24, We14, wqoff);
    prep_compose_kernel<<<256, 256, 0, stream>>>(Wu, Wv, Wk, Wq, bv, bq,
                                                 WuC4, Wqk4, bv2, bqk);
    xn_fused_kernel<<<dim3(64, 16), 256, 0, stream>>>(x, ln_in_g, ln_in_b, xnb);
    init_slots_kernel<<<B_ * K_, 256, 0, stream>>>(noise, slot_mu, slot_ls,
                                                   slots, usum, denom);
    qt_kernel<<<dim3(4, B_ * K_), 256, 0, stream>>>(slots, ln_sl_g, ln_sl_b,
                                                    Wqk4, bqk, wqoff, qtbuf, qoffb);
    for (int it = 0; it < ITERS_; ++it) {
        attn_fused_kernel<<<dim3(64, 16), 256, 0, stream>>>(qtbuf, qoffb, xnb,
                                                            usum, denom);
        upd_wu_kernel<<<dim3(8, B_ * K_), 256, 0, stream>>>(slots, usum, denom,
                                                            WuC4, bu, bv2, nvbuf);
        upd_w1_kernel<<<dim3(8, B_ * K_), 256, 0, stream>>>(nvbuf, ln_mlp_g, ln_mlp_b,
                                                            W14, b1, hbuf, usum, denom);
        upd_w2_kernel<<<dim3(8, B_ * K_), 256, 0, stream>>>(
            nvbuf, hbuf, W24, b2, (it < ITERS_ - 1) ? slots : out);
        if (it < ITERS_ - 1)
            qt_kernel<<<dim3(4, B_ * K_), 256, 0, stream>>>(slots, ln_sl_g, ln_sl_b,
                                                            Wqk4, bqk, wqoff, qtbuf, qoffb);
    }
    head_kernel<<<B_ * K_, 256, 0, stream>>>(out, We14, be1, We2, be2, out);
}